// Round 7
// baseline (563.486 us; speedup 1.0000x reference)
//
#include <hip/hip_runtime.h>

typedef unsigned short ushort_t;
typedef __attribute__((ext_vector_type(8))) __bf16 bf16x8;
typedef __attribute__((ext_vector_type(4))) float f32x4;

#define SEQ 8192
#define DIN 1024
#define DOUT 1024

// epilogue output modes
#define OM_BF16 0
#define OM_EXP  2   // bf16 exp2(scale*acc) store + per-block partial row-sums -> rsp
#define OM_NORM 3   // f32 store of acc * invrs[row]

__device__ __forceinline__ ushort_t f2bf(float f) {
  union { float f; unsigned u; } c; c.f = f;
  unsigned u = c.u;
  return (ushort_t)((u + 0x7fffu + ((u >> 16) & 1u)) >> 16);  // RNE
}

__device__ __forceinline__ void async16(ushort_t* lds, const ushort_t* g) {
  __builtin_amdgcn_global_load_lds(
      (__attribute__((address_space(1))) void*)g,
      (__attribute__((address_space(3))) void*)lds, 16, 0, 0);
}

template <int N>
__device__ __forceinline__ void waitv() {
  asm volatile("s_waitcnt vmcnt(%0)" :: "n"(N) : "memory");
}

// counted LDS wait + rule-18 fence (MFMA must not hoist above the wait)
template <int N>
__device__ __forceinline__ void waitlgkm() {
  asm volatile("s_waitcnt lgkmcnt(%0)" :: "n"(N) : "memory");
  __builtin_amdgcn_sched_barrier(0);
}

// inline-asm ds_read_b128 with compile-time immediate offset. The compiler
// cannot sink these to their uses (volatile), so reads stay grouped and the
// counted lgkmcnt plan holds. Address sampled at issue -> no WAR on addr.
template <int IMM>
__device__ __forceinline__ bf16x8 dsr(const ushort_t* p) {
  bf16x8 d;
  auto p3 = (const __attribute__((address_space(3))) ushort_t*)p;
  asm volatile("ds_read_b128 %0, %1 offset:%2"
               : "=v"(d) : "v"(p3), "n"(IMM));
  return d;
}

template <int BASE, int CNT, int IDX = 0>
__device__ __forceinline__ void readN(bf16x8* dst, const ushort_t* p) {
  if constexpr (IDX < CNT) {
    dst[IDX] = dsr<BASE + IDX * 2048>(p);
    readN<BASE, CNT, IDX + 1>(dst, p);
  }
}

template <int V> struct IC { static constexpr int value = V; };

// ------- fused fp32 -> bf16 convert for x, Wq, Wk, Wv -------
__global__ __launch_bounds__(256) void cvt_all_kernel(
    const float* __restrict__ x, const float* __restrict__ wq,
    const float* __restrict__ wk, const float* __restrict__ wv,
    ushort_t* __restrict__ xb, ushort_t* __restrict__ wqkb,
    ushort_t* __restrict__ wvb) {
  int b = blockIdx.x;
  const float* src;
  ushort_t* dst;
  int idx;
  if (b < 8192) {
    src = x; dst = xb; idx = b * 256 + threadIdx.x;
  } else {
    int r = b - 8192;
    int w = r >> 10;
    idx = (r & 1023) * 256 + threadIdx.x;
    if (w == 0)      { src = wq; dst = wqkb; }
    else if (w == 1) { src = wk; dst = wqkb + DOUT * DIN; }
    else             { src = wv; dst = wvb; }
  }
  float4 f = ((const float4*)src)[idx];
  ushort4 o;
  o.x = f2bf(f.x); o.y = f2bf(f.y); o.z = f2bf(f.z); o.w = f2bf(f.w);
  ((ushort4*)dst)[idx] = o;
}

// ------- rowsum partials [32][SEQ] -> invrs[SEQ] = 1/sum -------
__global__ __launch_bounds__(256) void rowsum_inv_kernel(const float* __restrict__ rsp,
                                                         float* __restrict__ invrs) {
  int r = blockIdx.x * 256 + threadIdx.x;
  float s = 0.f;
  #pragma unroll
  for (int p2 = 0; p2 < 32; ++p2) s += rsp[p2 * SEQ + r];
  invrs[r] = 1.0f / s;
}

// ---------------- GEMM: C[M][N] = A[M][K] @ B[N][K]^T ----------------
// Round-7: per-wave pipelined K-loop (AITER pattern, plain-HIP + inline asm).
// BMxBN tile, BK=64, 512 thr = 8 waves (2M x 4N), wave tile (BM/2)x(BN/4),
// mfma_f32_16x16x32_bf16, acc[MI][NIfr].
// Per K-tile (ONE barrier, ONE vmcnt):
//   issue g1 = aL0+bL0 (asm ds_read), stage FULL next tile (gload_lds),
//   issue g2 = aH0+bH0;
//   lgkm<=|g2|  -> g1 done -> MFMA q00/ks0       (g2 drains under MFMA)
//   issue g3 = aL1+bL1; lgkm<=|g3| -> g2 done -> MFMA q01,q10,q11/ks0
//   issue g4 = aH1+bH1; lgkm<=|g4| -> g3 done -> MFMA q00/ks1
//   lgkm<=0 -> g4 done -> MFMA q01,q10,q11/ks1
//   vmcnt(0)  (next-tile stage landed; issued ~2500 cyc earlier -> free)
//   s_barrier (tile boundary)
// Correctness: DS ops complete in-order per wave -> counted lgkm exact;
// every wave reaches lgkm==0 before its tile-end barrier -> next stage can
// overwrite the other buffer safely; sched_barrier(0) after each wait stops
// MFMA hoisting above inline-asm waits (rule #18). E/O tile bodies resolve
// the buffer at compile time so all ds_read offsets are immediates.
// LDS swizzle (proven r4-r6): chunk slot ^= row&7 on global source + read imm
// base; slot XOR is lane-constant per ks -> 2 base pointers per operand.
template <int OUTMODE, int SUPER, int BM, int BN>
__global__ __launch_bounds__(512, 2) void gemmp(
    const ushort_t* __restrict__ A, const ushort_t* __restrict__ B,
    void* __restrict__ C, int lda, int ldb, int ldc, int K, float scale,
    float* __restrict__ rsp, const float* __restrict__ invrs) {
  constexpr int WM = BM / 2, WN = BN / 4;
  constexpr int MI = BM / 32, NIfr = BN / 64;
  constexpr int MH = MI / 2, NH = NIfr / 2;
  constexpr int AST = BM * 64, BST = BN * 64;     // elems per buffer
  constexpr int LAT = BM / 64, LBT = BN / 64;     // gload_lds per thread/tile
  __shared__ ushort_t As[2 * AST];
  __shared__ ushort_t Bs[2 * BST];

  const int t = threadIdx.x;
  const int lane = t & 63;
  const int wave = t >> 6;
  const int wr = wave >> 2, wc = wave & 3;
  const int quad = lane >> 4, r16 = lane & 15;

  const int gx = gridDim.x;
  const int nwg = gx * gridDim.y;
  const int bid = blockIdx.y * gx + blockIdx.x;
  int mt, nt;
  if (SUPER == 1) {
    // 32x32 grid only: XCD (x>>2, x&3) owns 16mt x 8nt, walked in 4x8 chunks
    int x = bid & 7, l = bid >> 3;
    mt = ((x >> 2) << 4) + ((l >> 5) << 2) + ((l >> 3) & 3);
    nt = ((x & 3) << 3) + (l & 7);
  } else {
    const int q8 = nwg >> 3;
    const int b2 = (bid & 7) * q8 + (bid >> 3);
    mt = b2 / gx;
    nt = b2 - mt * gx;
  }
  const int rowBase = mt * BM;
  const int colBase = nt * BN;

  // staging source offsets (elements), full tile per group; +64 per tile
  unsigned offA[LAT], offB[LBT];
  #pragma unroll
  for (int i = 0; i < LAT; ++i) {
    int c = t + i * 512, row = c >> 3, sl = c & 7;
    offA[i] = (unsigned)((rowBase + row) * lda + ((sl ^ (row & 7)) << 3));
  }
  #pragma unroll
  for (int i = 0; i < LBT; ++i) {
    int c = t + i * 512, row = c >> 3, sl = c & 7;
    offB[i] = (unsigned)((colBase + row) * ldb + ((sl ^ (row & 7)) << 3));
  }

  auto stage = [&](int buf) {
    #pragma unroll
    for (int i = 0; i < LAT; ++i) {
      async16(&As[buf * AST + (t + i * 512) * 8], A + offA[i]); offA[i] += 64;
    }
    #pragma unroll
    for (int i = 0; i < LBT; ++i) {
      async16(&Bs[buf * BST + (t + i * 512) * 8], B + offB[i]); offB[i] += 64;
    }
  };

  // read base pointers: swizzled slot is lane-constant per ks
  const ushort_t* aP0 = As + (wr * WM + r16) * 64 + ((quad ^ (r16 & 7)) << 3);
  const ushort_t* aP1 = As + (wr * WM + r16) * 64 + (((4 + quad) ^ (r16 & 7)) << 3);
  const ushort_t* bP0 = Bs + (wc * WN + r16) * 64 + ((quad ^ (r16 & 7)) << 3);
  const ushort_t* bP1 = Bs + (wc * WN + r16) * 64 + (((4 + quad) ^ (r16 & 7)) << 3);

  f32x4 acc[MI][NIfr] = {};

#define MMC(MHI, NHI, AF, BF)                                                  \
  __builtin_amdgcn_s_setprio(1);                                               \
  _Pragma("unroll") for (int mi = 0; mi < MH; ++mi)                            \
    _Pragma("unroll") for (int ni = 0; ni < NH; ++ni)                          \
      acc[(MHI) * MH + mi][(NHI) * NH + ni] =                                  \
          __builtin_amdgcn_mfma_f32_16x16x32_bf16(                             \
              AF[mi], BF[ni], acc[(MHI) * MH + mi][(NHI) * NH + ni], 0, 0, 0); \
  __builtin_amdgcn_s_setprio(0);

  auto tile = [&](auto BUFC, bool doStage) {
    constexpr int buf = decltype(BUFC)::value;
    constexpr int AB = buf * AST * 2;   // byte offsets into As/Bs
    constexpr int BB = buf * BST * 2;
    bf16x8 aL0[MH], aH0[MH], bL0[NH], bH0[NH];
    bf16x8 aL1[MH], aH1[MH], bL1[NH], bH1[NH];
    // g1
    readN<AB, MH>(aL0, aP0);
    readN<BB, NH>(bL0, bP0);
    if (doStage) stage(buf ^ 1);
    // g2
    readN<AB + MH * 2048, MH>(aH0, aP0);
    readN<BB + NH * 2048, NH>(bH0, bP0);
    waitlgkm<MH + NH>();                 // g1 landed; g2 in flight
    MMC(0, 0, aL0, bL0);
    // g3
    readN<AB, MH>(aL1, aP1);
    readN<BB, NH>(bL1, bP1);
    waitlgkm<MH + NH>();                 // g2 landed; g3 in flight
    MMC(0, 1, aL0, bH0);
    MMC(1, 0, aH0, bL0);
    MMC(1, 1, aH0, bH0);
    // g4
    readN<AB + MH * 2048, MH>(aH1, aP1);
    readN<BB + NH * 2048, NH>(bH1, bP1);
    waitlgkm<MH + NH>();                 // g3 landed; g4 in flight
    MMC(0, 0, aL1, bL1);
    waitlgkm<0>();                       // g4 landed; ALL reads of this tile done
    MMC(0, 1, aL1, bH1);
    MMC(1, 0, aH1, bL1);
    MMC(1, 1, aH1, bH1);
    waitv<0>();                          // next-tile stage landed (issued early)
    __builtin_amdgcn_s_barrier();        // tile boundary
  };

  // prologue: tile 0 -> buf 0
  stage(0);
  waitv<0>();
  __builtin_amdgcn_s_barrier();

  const int NI2 = K / 128;
  for (int it = 0; it < NI2; ++it) {
    tile(IC<0>{}, true);                 // E: reads buf0, stages buf1
    tile(IC<1>{}, it + 1 < NI2);         // O: reads buf1, stages buf0
  }

  // ---- epilogue: C/D layout col=lane&15, row=quad*4+reg ----
  float iv[MI][4];
  if constexpr (OUTMODE == OM_NORM) {
    #pragma unroll
    for (int mi = 0; mi < MI; ++mi)
      #pragma unroll
      for (int r = 0; r < 4; ++r)
        iv[mi][r] = invrs[rowBase + wr * WM + mi * 16 + quad * 4 + r];
  }

  float psum[MI][4];
  if constexpr (OUTMODE == OM_EXP) {
    #pragma unroll
    for (int mi = 0; mi < MI; ++mi)
      #pragma unroll
      for (int r = 0; r < 4; ++r) psum[mi][r] = 0.f;
  }

  #pragma unroll
  for (int mi = 0; mi < MI; ++mi)
    #pragma unroll
    for (int ni = 0; ni < NIfr; ++ni)
      #pragma unroll
      for (int r = 0; r < 4; ++r) {
        int grow = rowBase + wr * WM + mi * 16 + quad * 4 + r;
        int gcol = colBase + wc * WN + ni * 16 + r16;
        float a = acc[mi][ni][r];
        if constexpr (OUTMODE == OM_BF16) {
          ((ushort_t*)C)[(size_t)grow * ldc + gcol] = f2bf(a * scale);
        } else if constexpr (OUTMODE == OM_EXP) {
          float e = exp2f(a * scale);   // scale carries the log2(e) factor
          psum[mi][r] += e;
          ((ushort_t*)C)[(size_t)grow * ldc + gcol] = f2bf(e);
        } else {  // OM_NORM
          ((float*)C)[(size_t)grow * ldc + gcol] = a * iv[mi][r];
        }
      }

  if constexpr (OUTMODE == OM_EXP) {
    __syncthreads();                 // all LDS traffic done before reuse
    float* lds_rs = (float*)As;      // [4][256]
    #pragma unroll
    for (int mi = 0; mi < MI; ++mi)
      #pragma unroll
      for (int r = 0; r < 4; ++r) {
        float sv = psum[mi][r];
        sv += __shfl_xor(sv, 1, 64);
        sv += __shfl_xor(sv, 2, 64);
        sv += __shfl_xor(sv, 4, 64);
        sv += __shfl_xor(sv, 8, 64);
        if (r16 == 0)
          lds_rs[wc * 256 + wr * WM + mi * 16 + quad * 4 + r] = sv;
      }
    __syncthreads();
    if (t < 256)
      rsp[(size_t)nt * SEQ + rowBase + t] =
          lds_rs[t] + lds_rs[256 + t] + lds_rs[512 + t] + lds_rs[768 + t];
  }
#undef MMC
}

extern "C" void kernel_launch(void* const* d_in, const int* in_sizes, int n_in,
                              void* d_out, int out_size, void* d_ws, size_t ws_size,
                              hipStream_t stream) {
  const float* x  = (const float*)d_in[0];
  const float* Wq = (const float*)d_in[1];
  const float* Wk = (const float*)d_in[2];
  const float* Wv = (const float*)d_in[3];
  float* out = (float*)d_out;

  char* p = (char*)d_ws;
  ushort_t* xb   = (ushort_t*)p; p += (size_t)SEQ * DIN * 2;        // 16 MB
  ushort_t* wqkb = (ushort_t*)p; p += (size_t)2 * DOUT * DIN * 2;   //  4 MB (Wq|Wk)
  ushort_t* wvb  = (ushort_t*)p; p += (size_t)DOUT * DIN * 2;       //  2 MB
  ushort_t* qkb  = (ushort_t*)p; p += (size_t)SEQ * 2 * DOUT * 2;   // 32 MB ([S][2048], q|k)
  ushort_t* vtb  = (ushort_t*)p; p += (size_t)DOUT * SEQ * 2;       // 16 MB (v^T)
  float*    rsp  = (float*)p;    p += (size_t)64 * SEQ * 4;         //  2 MB partial rowsums
  float*    irs  = (float*)p;    p += (size_t)SEQ * 4;              // 32 KB 1/rowsum
  ushort_t* Sb   = (ushort_t*)p; p += (size_t)SEQ * SEQ * 2;        // 128 MB

  // fp32 -> bf16 for all four tensors (one launch)
  cvt_all_kernel<<<8192 + 3 * 1024, 256, 0, stream>>>(x, Wq, Wk, Wv, xb, wqkb, wvb);

  dim3 blk(512);
  // [q|k] = x @ [Wq|Wk]^T : M=8192, N=2048, K=1024 -> 8x32 = 256 blocks
  gemmp<OM_BF16, 0, 256, 256><<<dim3(2048 / 256, SEQ / 256), blk, 0, stream>>>(
      xb, wqkb, qkb, DIN, DIN, 2 * DOUT, DIN, 1.0f, nullptr, nullptr);

  // v^T = Wv @ x^T : M=1024, N=8192, K=1024 -> BM=128,BN=256: 32x8 = 256 blocks
  gemmp<OM_BF16, 0, 128, 256><<<dim3(SEQ / 256, DOUT / 128), blk, 0, stream>>>(
      wvb, xb, vtb, DIN, DIN, SEQ, DIN, 1.0f, nullptr, nullptr);

  // E = exp((q @ k^T)/32) via exp2, partial row sums -> rsp : 32x32 = 1024 blocks
  gemmp<OM_EXP, 1, 256, 256><<<dim3(SEQ / 256, SEQ / 256), blk, 0, stream>>>(
      qkb, qkb + DOUT, Sb, 2 * DOUT, 2 * DOUT, SEQ, DIN,
      0.03125f * 1.44269504f, rsp, nullptr);

  // invrs[r] = 1 / sum_p rsp[p][r]  (32 partial tiles)
  rowsum_inv_kernel<<<SEQ / 256, 256, 0, stream>>>(rsp, irs);

  // out = (E @ v) * invrs : M=8192, N=1024, K=8192 -> BM=128,BN=256: 4x64 = 256 blocks
  gemmp<OM_NORM, 0, 128, 256><<<dim3(DOUT / 256, SEQ / 128), blk, 0, stream>>>(
      Sb, vtb, out, SEQ, SEQ, DOUT, SEQ, 1.0f, nullptr, irs);
}